// Round 9
// baseline (378.817 us; speedup 1.0000x reference)
//
#include <hip/hip_runtime.h>
#include <stdint.h>

typedef unsigned short u16;
typedef u16   u16x4v __attribute__((ext_vector_type(4)));
typedef u16   u16x8v __attribute__((ext_vector_type(8)));
typedef short s16x8v __attribute__((ext_vector_type(8)));
typedef float f32x4v __attribute__((ext_vector_type(4)));

#define DEV static __device__ __forceinline__

// fp32 -> bf16 round-to-nearest-even (scalar)
DEV u16 f2bf(float f){
  union { float f; unsigned u; } v; v.f = f;
  unsigned r = v.u + 0x7FFFu + ((v.u >> 16) & 1u);
  return (u16)(r >> 16);
}

DEV f32x4v mfma16(s16x8v a, s16x8v b, f32x4v c){
  return __builtin_amdgcn_mfma_f32_16x16x32_bf16(a, b, c, 0, 0, 0);
}

// ---------------------------------------------------------------------------
// k_wall: all weight prep in one launch. (unchanged — passed)
__global__ __launch_bounds__(256) void k_wall(const float* __restrict__ w_qs,
                                              const float* __restrict__ w_ks,
                                              const float* __restrict__ w_vs,
                                              const float* __restrict__ proj_w,
                                              u16* __restrict__ wt, u16* __restrict__ wtp,
                                              float qscale){
  int gid = blockIdx.x;
  int tsel = gid >> 10;
  int e = (gid & 1023) * 256 + threadIdx.x;
  if(tsel == 3){
    wtp[e] = f2bf(proj_w[e]);
  } else {
    const float* w = tsel == 0 ? w_qs : (tsel == 1 ? w_ks : w_vs);
    float sc = tsel == 0 ? qscale : 1.0f;
    int n = e >> 9, d = e & 511;
    int h = n >> 6, kk = n & 63;
    wt[tsel * 262144 + n * 512 + d] = f2bf(w[h * 32768 + d * 64 + kk] * sc);
  }
}

// ---------------------------------------------------------------------------
// Fused QKV projection (unchanged — passed).
__global__ __launch_bounds__(256) void k_qkv(const float* __restrict__ Q,
                                             const float* __restrict__ K,
                                             const float* __restrict__ V,
                                             const u16* __restrict__ Wt,
                                             u16* __restrict__ qhh, u16* __restrict__ khh,
                                             u16* __restrict__ vtt){
  __shared__ __align__(16) u16 Xs[32 * 520];
  const int t = threadIdx.x;
  const int lane = t & 63, w = t >> 6;
  const int g = lane >> 4, li = lane & 15;
  const int i0 = blockIdx.x * 32;
  const int y = blockIdx.y;
  const int tsel = y >> 1;
  const float* X = tsel == 0 ? Q : (tsel == 1 ? K : V);
  const int n0 = (y & 1) * 256 + w * 64;

  #pragma unroll
  for(int it = 0; it < 16; ++it){
    int s = it * 256 + t, row = s >> 7, c4 = s & 127;
    f32x4v xv = *(const f32x4v*)(X + (size_t)(i0 + row) * 512 + c4 * 4);
    u16x4v bv; bv[0]=f2bf(xv[0]); bv[1]=f2bf(xv[1]); bv[2]=f2bf(xv[2]); bv[3]=f2bf(xv[3]);
    *(u16x4v*)(Xs + row * 520 + c4 * 4) = bv;
  }
  __syncthreads();

  const int wbase = tsel * 512 + n0;
  const u16* wp0 = Wt + (size_t)(wbase +  0 + li) * 512 + g * 8;
  const u16* wp1 = Wt + (size_t)(wbase + 16 + li) * 512 + g * 8;
  const u16* wp2 = Wt + (size_t)(wbase + 32 + li) * 512 + g * 8;
  const u16* wp3 = Wt + (size_t)(wbase + 48 + li) * 512 + g * 8;

#define LOADW(S, c) { \
  S##0 = *(const s16x8v*)(wp0 + (c) * 32); \
  S##1 = *(const s16x8v*)(wp1 + (c) * 32); \
  S##2 = *(const s16x8v*)(wp2 + (c) * 32); \
  S##3 = *(const s16x8v*)(wp3 + (c) * 32); }
#define COMPW(S, c) { \
  int k0 = (c) * 32 + g * 8; \
  s16x8v a0 = *(const s16x8v*)(Xs + li * 520 + k0); \
  s16x8v a1 = *(const s16x8v*)(Xs + (16 + li) * 520 + k0); \
  acc[0][0] = mfma16(a0, S##0, acc[0][0]); acc[1][0] = mfma16(a1, S##0, acc[1][0]); \
  acc[0][1] = mfma16(a0, S##1, acc[0][1]); acc[1][1] = mfma16(a1, S##1, acc[1][1]); \
  acc[0][2] = mfma16(a0, S##2, acc[0][2]); acc[1][2] = mfma16(a1, S##2, acc[1][2]); \
  acc[0][3] = mfma16(a0, S##3, acc[0][3]); acc[1][3] = mfma16(a1, S##3, acc[1][3]); }

  f32x4v acc[2][4] = {};
  s16x8v wA0, wA1, wA2, wA3, wB0, wB1, wB2, wB3;
  LOADW(wA, 0);
  #pragma unroll
  for(int c = 0; c < 16; c += 2){
    LOADW(wB, c + 1);
    COMPW(wA, c);
    if(c + 2 < 16) LOADW(wA, c + 2);
    COMPW(wB, c + 1);
  }
#undef LOADW
#undef COMPW

  if(tsel < 2){
    u16* Y = tsel == 0 ? qhh : khh;
    #pragma unroll
    for(int rg = 0; rg < 2; ++rg)
      #pragma unroll
      for(int j = 0; j < 4; ++j){
        int n = n0 + j * 16 + li, h = n >> 6, dk = n & 63;
        #pragma unroll
        for(int r = 0; r < 4; ++r){
          int i = i0 + rg * 16 + g * 4 + r, bb = i >> 11, m = i & 2047;
          Y[((size_t)(h * 4 + bb) * 2048 + m) * 64 + dk] = f2bf(acc[rg][j][r]);
        }
      }
  } else {
    #pragma unroll
    for(int rg = 0; rg < 2; ++rg)
      #pragma unroll
      for(int j = 0; j < 4; ++j){
        int n = n0 + j * 16 + li;
        u16x4v pk;
        #pragma unroll
        for(int r = 0; r < 4; ++r) pk[r] = f2bf(acc[rg][j][r]);
        *(u16x4v*)(vtt + (size_t)n * 8192 + i0 + g * 8 + rg * 4) = pk;
      }
  }
}

// ---------------------------------------------------------------------------
// k_pv: SINGLE-pass attention, no stores in the loop (pure-load vmcnt FIFO).
// Unnormalized PV: acc += exp2(z) * V, l += exp2(z); O = acc / l at the end.
// m-split block (2 qs x 2 mh waves); writes XC + lbtab (-log2 l).

#define LOADK(B, ht) { \
  const u16* _p = kp + (size_t)(ht) * 2048; \
  B##0 = *(const s16x8v*)(_p); \
  B##1 = *(const s16x8v*)(_p + 32); \
  B##2 = *(const s16x8v*)(_p + 1024); \
  B##3 = *(const s16x8v*)(_p + 1056); }

#define LOADV(B, ht) { \
  const u16* _p = vp + (ht) * 32; \
  B##0 = *(const s16x8v*)(_p); \
  B##1 = *(const s16x8v*)(_p + 131072); \
  B##2 = *(const s16x8v*)(_p + 262144); \
  B##3 = *(const s16x8v*)(_p + 393216); }

#define PVH(KB, VB, bqa, bqb, qs_, sA, sB) { \
  f32x4v z0 = {}, z1 = {}; \
  z0 = mfma16(KB##0, bqa, z0); z0 = mfma16(KB##1, bqb, z0); \
  z1 = mfma16(KB##2, bqa, z1); z1 = mfma16(KB##3, bqb, z1); \
  f32x4v p0, p1; \
  _Pragma("unroll") for(int r = 0; r < 4; ++r){ p0[r] = exp2f(z0[r]); p1[r] = exp2f(z1[r]); } \
  _Pragma("unroll") for(int r = 0; r < 4; ++r){ sA[r] += p0[r]; sB[r] += p1[r]; } \
  union { u16 hh[8]; s16x8v v; } _u; \
  _Pragma("unroll") for(int r = 0; r < 4; ++r){ _u.hh[r] = f2bf(p0[r]); _u.hh[4 + r] = f2bf(p1[r]); } \
  acc##qs_##0 = mfma16(_u.v, VB##0, acc##qs_##0); \
  acc##qs_##1 = mfma16(_u.v, VB##1, acc##qs_##1); \
  acc##qs_##2 = mfma16(_u.v, VB##2, acc##qs_##2); \
  acc##qs_##3 = mfma16(_u.v, VB##3, acc##qs_##3); }

#define PVSTEP(KB, VB) { \
  PVH(KB, VB, bq00, bq01, 0, s00, s01); \
  PVH(KB, VB, bq10, bq11, 1, s10, s11); }

__global__ __launch_bounds__(256, 3) void k_pv(const u16* __restrict__ QHH, const u16* __restrict__ KHH,
                                               const u16* __restrict__ VTT,
                                               u16* __restrict__ XC, float* __restrict__ LB){
  __shared__ float Lp[2][2][32];        // [qs][mh][row]
  __shared__ float AccS[2][32][64];     // [qs][elem][lane]  = 16 KB
  const int t = threadIdx.x, lane = t & 63, w = t >> 6;
  const int g = lane >> 4, li = lane & 15;
  const int qs = w >> 1, mh = w & 1;
  const int gid = blockIdx.x;                // 0..1023
  const int xcd = gid & 7, rem = gid >> 3;   // rem 0..127
  const int qt = rem & 31;
  const int hb = xcd * 4 + (rem >> 5);
  const int h = hb >> 2, b = hb & 3;
  const size_t base_hb = (size_t)hb * 2048;
  const int qbase = qt * 64 + qs * 32;

  s16x8v bq00, bq01, bq10, bq11;
  {
    const u16* qp0 = QHH + (base_hb + qbase + li) * 64 + g * 8;
    const u16* qp1 = QHH + (base_hb + qbase + 16 + li) * 64 + g * 8;
    bq00 = *(const s16x8v*)(qp0); bq01 = *(const s16x8v*)(qp0 + 32);
    bq10 = *(const s16x8v*)(qp1); bq11 = *(const s16x8v*)(qp1 + 32);
  }
  const u16* kp = KHH + (base_hb + li) * 64 + g * 8 + (size_t)mh * 65536;
  const u16* vp = VTT + (size_t)(h * 64 + li) * 8192 + b * 2048 + g * 8 + mh * 1024;

  f32x4v s00 = {}, s01 = {}, s10 = {}, s11 = {};
  f32x4v acc00 = {}, acc01 = {}, acc02 = {}, acc03 = {};
  f32x4v acc10 = {}, acc11 = {}, acc12 = {}, acc13 = {};
  {
    s16x8v kA0, kA1, kA2, kA3, kB0, kB1, kB2, kB3;
    s16x8v vA0, vA1, vA2, vA3, vB0, vB1, vB2, vB3;
    LOADK(kA, 0); LOADV(vA, 0);
    for(int ht = 0; ht < 30; ht += 2){
      LOADK(kB, ht + 1); LOADV(vB, ht + 1);
      PVSTEP(kA, vA);
      LOADK(kA, ht + 2); LOADV(vA, ht + 2);
      PVSTEP(kB, vB);
    }
    LOADK(kB, 31); LOADV(vB, 31);
    PVSTEP(kA, vA);
    PVSTEP(kB, vB);
  }

  // ---- row sums -> Lp ----
  float l0 = (s00[0]+s00[1]+s00[2]+s00[3]) + (s01[0]+s01[1]+s01[2]+s01[3]);
  float l1 = (s10[0]+s10[1]+s10[2]+s10[3]) + (s11[0]+s11[1]+s11[2]+s11[3]);
  l0 += __shfl_xor(l0, 16, 64); l0 += __shfl_xor(l0, 32, 64);
  l1 += __shfl_xor(l1, 16, 64); l1 += __shfl_xor(l1, 32, 64);
  if(lane < 16){ Lp[qs][mh][li] = l0; Lp[qs][mh][16 + li] = l1; }
  // ---- PV partials from mh==1 into LDS ----
  if(mh == 1){
    #pragma unroll
    for(int r = 0; r < 4; ++r){
      AccS[qs][ 0 + r][lane] = acc00[r];
      AccS[qs][ 4 + r][lane] = acc01[r];
      AccS[qs][ 8 + r][lane] = acc02[r];
      AccS[qs][12 + r][lane] = acc03[r];
      AccS[qs][16 + r][lane] = acc10[r];
      AccS[qs][20 + r][lane] = acc11[r];
      AccS[qs][24 + r][lane] = acc12[r];
      AccS[qs][28 + r][lane] = acc13[r];
    }
  }
  __syncthreads();
  // lbtab for the writer kernel: lb = -log2(l_total)
  if(mh == 0 && lane < 32)
    LB[base_hb + qbase + lane] = -__log2f(Lp[qs][0][lane] + Lp[qs][1][lane]);

  if(mh == 0){
    float rlA[4], rlB[4];
    #pragma unroll
    for(int r = 0; r < 4; ++r){
      rlA[r] = 1.0f / (Lp[qs][0][g * 4 + r]      + Lp[qs][1][g * 4 + r]);
      rlB[r] = 1.0f / (Lp[qs][0][16 + g * 4 + r] + Lp[qs][1][16 + g * 4 + r]);
    }
    #pragma unroll
    for(int r = 0; r < 4; ++r){
      acc00[r] = (acc00[r] + AccS[qs][ 0 + r][lane]) * rlA[r];
      acc01[r] = (acc01[r] + AccS[qs][ 4 + r][lane]) * rlA[r];
      acc02[r] = (acc02[r] + AccS[qs][ 8 + r][lane]) * rlA[r];
      acc03[r] = (acc03[r] + AccS[qs][12 + r][lane]) * rlA[r];
      acc10[r] = (acc10[r] + AccS[qs][16 + r][lane]) * rlB[r];
      acc11[r] = (acc11[r] + AccS[qs][20 + r][lane]) * rlB[r];
      acc12[r] = (acc12[r] + AccS[qs][24 + r][lane]) * rlB[r];
      acc13[r] = (acc13[r] + AccS[qs][28 + r][lane]) * rlB[r];
    }
    #pragma unroll
    for(int r = 0; r < 4; ++r){
      int row0 = qbase + g * 4 + r;
      int row1 = qbase + 16 + g * 4 + r;
      u16* x0 = XC + (size_t)(b * 2048 + row0) * 512 + h * 64 + li;
      u16* x1 = XC + (size_t)(b * 2048 + row1) * 512 + h * 64 + li;
      x0[0]  = f2bf(acc00[r]); x0[16] = f2bf(acc01[r]); x0[32] = f2bf(acc02[r]); x0[48] = f2bf(acc03[r]);
      x1[0]  = f2bf(acc10[r]); x1[16] = f2bf(acc11[r]); x1[32] = f2bf(acc12[r]); x1[48] = f2bf(acc13[r]);
    }
  }
}

// ---------------------------------------------------------------------------
// k_att_write: dedicated ATT writer. Each wave: 16 q-rows x all 2048 keys.
// K loads hoisted into 2-step register bursts, double-buffered, so the
// once-per-2-steps load-wait sits ~2 compute steps behind the stores it
// must drain (in-order vmcnt coupling amortized).

#define LB8(S, s) { \
  const u16* _p = kp + (size_t)(s) * 2048; \
  S##0 = *(const s16x8v*)(_p);        S##1 = *(const s16x8v*)(_p + 32); \
  S##2 = *(const s16x8v*)(_p + 1024); S##3 = *(const s16x8v*)(_p + 1056); \
  S##4 = *(const s16x8v*)(_p + 2048); S##5 = *(const s16x8v*)(_p + 2080); \
  S##6 = *(const s16x8v*)(_p + 3072); S##7 = *(const s16x8v*)(_p + 3104); }

#define WSTEP1(A0, A1, A2, A3, ht) { \
  f32x4v z0 = {}, z1 = {}; \
  z0 = mfma16(A0, bq0, z0); z0 = mfma16(A1, bq1, z0); \
  z1 = mfma16(A2, bq0, z1); z1 = mfma16(A3, bq1, z1); \
  f32x4v p0, p1; \
  _Pragma("unroll") for(int r = 0; r < 4; ++r){ p0[r] = exp2f(z0[r] + lb); p1[r] = exp2f(z1[r] + lb); } \
  float* _ab = attb + li * 2048 + (ht) * 32 + g * 4; \
  __builtin_nontemporal_store(p0, (f32x4v*)(_ab)); \
  __builtin_nontemporal_store(p1, (f32x4v*)(_ab + 16)); }

#define CS2(S, s) { \
  WSTEP1(S##0, S##1, S##2, S##3, s); \
  WSTEP1(S##4, S##5, S##6, S##7, (s) + 1); }

__global__ __launch_bounds__(256, 4) void k_att_write(const u16* __restrict__ QHH,
                                                      const u16* __restrict__ KHH,
                                                      const float* __restrict__ LB,
                                                      float* __restrict__ ATT){
  const int t = threadIdx.x, lane = t & 63, w = t >> 6;
  const int g = lane >> 4, li = lane & 15;
  const int gid = blockIdx.x;                // 0..1023
  const int xcd = gid & 7, rem = gid >> 3;
  const int qt = rem & 31;                   // 64-row tile
  const int hb = xcd * 4 + (rem >> 5);
  const size_t base_hb = (size_t)hb * 2048;
  const int rowbase = qt * 64 + w * 16;      // this wave's 16 q-rows

  s16x8v bq0, bq1;
  {
    const u16* qp = QHH + (base_hb + rowbase + li) * 64 + g * 8;
    bq0 = *(const s16x8v*)(qp); bq1 = *(const s16x8v*)(qp + 32);
  }
  const float lb = LB[base_hb + rowbase + li];
  const u16* kp = KHH + (base_hb + li) * 64 + g * 8;
  float* attb = ATT + (base_hb + rowbase) * 2048;

  s16x8v kA0, kA1, kA2, kA3, kA4, kA5, kA6, kA7;
  s16x8v kB0, kB1, kB2, kB3, kB4, kB5, kB6, kB7;
  LB8(kA, 0); LB8(kB, 2);
  for(int ht = 0; ht < 60; ht += 4){
    CS2(kA, ht);
    LB8(kA, ht + 4);
    CS2(kB, ht + 2);
    LB8(kB, ht + 6);
  }
  CS2(kA, 60);
  CS2(kB, 62);
}

// ---------------------------------------------------------------------------
// Out-projection + bias + residual + LayerNorm (unchanged — passed).
__global__ __launch_bounds__(512) void k_out(const u16* __restrict__ Xb,
                                             const u16* __restrict__ Wtp,
                                             float* __restrict__ Yf,
                                             const float* __restrict__ bias,
                                             const float* __restrict__ resid,
                                             const float* __restrict__ a2,
                                             const float* __restrict__ b2){
  __shared__ __align__(16) u16 Xs[16 * 520];
  __shared__ float sred[8][16], sqred[8][16], muL[16], rsL[16];
  const int t = threadIdx.x;
  const int lane = t & 63, w = t >> 6;
  const int g = lane >> 4, li = lane & 15;
  const int i0 = blockIdx.x * 16;
  const int n0 = w * 64;

  #pragma unroll
  for(int it = 0; it < 2; ++it){
    int s = it * 512 + t, row = s >> 6, c8 = s & 63;
    u16x8v xv = *(const u16x8v*)(Xb + (size_t)(i0 + row) * 512 + c8 * 8);
    *(u16x8v*)(Xs + row * 520 + c8 * 8) = xv;
  }
  __syncthreads();

  const u16* wp0 = Wtp + (size_t)(n0 +  0 + li) * 512 + g * 8;
  const u16* wp1 = Wtp + (size_t)(n0 + 16 + li) * 512 + g * 8;
  const u16* wp2 = Wtp + (size_t)(n0 + 32 + li) * 512 + g * 8;
  const u16* wp3 = Wtp + (size_t)(n0 + 48 + li) * 512 + g * 8;

#define LOADW(S, c) { \
  S##0 = *(const s16x8v*)(wp0 + (c) * 32); \
  S##1 = *(const s16x8v*)(wp1 + (c) * 32); \
  S##2 = *(const s16x8v*)(wp2 + (c) * 32); \
  S##3 = *(const s16x8v*)(wp3 + (c) * 32); }
#define COMPW(S, c) { \
  int k0 = (c) * 32 + g * 8; \
  s16x8v a0 = *(const s16x8v*)(Xs + li * 520 + k0); \
  acc[0] = mfma16(a0, S##0, acc[0]); \
  acc[1] = mfma16(a0, S##1, acc[1]); \
  acc[2] = mfma16(a0, S##2, acc[2]); \
  acc[3] = mfma16(a0, S##3, acc[3]); }

  f32x4v acc[4] = {};
  s16x8v wA0, wA1, wA2, wA3, wB0, wB1, wB2, wB3;
  LOADW(wA, 0);
  #pragma unroll
  for(int c = 0; c < 16; c += 2){
    LOADW(wB, c + 1);
    COMPW(wA, c);
    if(c + 2 < 16) LOADW(wA, c + 2);
    COMPW(wB, c + 1);
  }
#undef LOADW
#undef COMPW

  float zres[4][4];
  #pragma unroll
  for(int j = 0; j < 4; ++j){
    int n = n0 + j * 16 + li;
    float bv = bias[n];
    #pragma unroll
    for(int r = 0; r < 4; ++r){
      int i = i0 + g * 4 + r;
      zres[j][r] = acc[j][r] + bv + resid[(size_t)i * 512 + n];
    }
  }
  #pragma unroll
  for(int r = 0; r < 4; ++r){
    float S = 0.f, SQ = 0.f;
    #pragma unroll
    for(int j = 0; j < 4; ++j){ float zz = zres[j][r]; S += zz; SQ += zz * zz; }
    #pragma unroll
    for(int off = 1; off < 16; off <<= 1){ S += __shfl_xor(S, off, 16); SQ += __shfl_xor(SQ, off, 16); }
    if(li == 0){ sred[w][g * 4 + r] = S; sqred[w][g * 4 + r] = SQ; }
  }
  __syncthreads();
  if(t < 16){
    float S = 0.f, SQ = 0.f;
    #pragma unroll
    for(int ww = 0; ww < 8; ++ww){ S += sred[ww][t]; SQ += sqred[ww][t]; }
    float mu = S * (1.0f / 512.0f);
    float var = (SQ - 512.0f * mu * mu) * (1.0f / 511.0f);
    muL[t] = mu;
    rsL[t] = 1.0f / (sqrtf(fmaxf(var, 0.0f)) + 1e-3f);
  }
  __syncthreads();
  #pragma unroll
  for(int r = 0; r < 4; ++r){
    int rloc = g * 4 + r;
    float mu = muL[rloc], rs = rsL[rloc];
    size_t ib = (size_t)(i0 + rloc) * 512;
    #pragma unroll
    for(int j = 0; j < 4; ++j){
      int n = n0 + j * 16 + li;
      Yf[ib + n] = (zres[j][r] - mu) * rs * a2[n] + b2[n];
    }
  }
}

// ---------------------------------------------------------------------------
extern "C" void kernel_launch(void* const* d_in, const int* in_sizes, int n_in,
                              void* d_out, int out_size, void* d_ws, size_t ws_size,
                              hipStream_t stream){
  const float* q      = (const float*)d_in[0];
  const float* k      = (const float*)d_in[1];
  const float* v      = (const float*)d_in[2];
  const float* w_qs   = (const float*)d_in[3];
  const float* w_ks   = (const float*)d_in[4];
  const float* w_vs   = (const float*)d_in[5];
  const float* proj_w = (const float*)d_in[6];
  const float* proj_b = (const float*)d_in[7];
  const float* a2     = (const float*)d_in[8];
  const float* b2     = (const float*)d_in[9];

  char* ws = (char*)d_ws;
  u16* wt    = (u16*)(ws);                       // 3 x 512KB (q-weights pre-scaled)
  u16* wtp   = (u16*)(ws + 1572864);             // 512KB proj_w bf16
  u16* qhh   = (u16*)(ws + 2097152);             // 8 MB head-major
  u16* khh   = (u16*)(ws + 10485760);            // 8 MB head-major
  u16* vtt   = (u16*)(ws + 18874368);            // 8 MB [n][perm(i)]
  u16* xc    = (u16*)(ws + 27262976);            // 8 MB [i][512]
  float* lbt = (float*)(ws + 35651584);          // 256 KB  -log2(l) per q-row

  float* out = (float*)d_out;                    // (4,2048,512) fp32
  float* att = out + 4194304;                    // (32,2048,2048) fp32

  // fold 1/sqrt(512) * log2(e) into the Q projection weights
  const float qscale = 0.06375872032774575f;

  k_wall     <<<dim3(4096), 256, 0, stream>>>(w_qs, w_ks, w_vs, proj_w, wt, wtp, qscale);
  k_qkv      <<<dim3(256, 6), 256, 0, stream>>>(q, k, v, wt, qhh, khh, vtt);
  k_pv       <<<dim3(1024), 256, 0, stream>>>(qhh, khh, vtt, xc, lbt);
  k_att_write<<<dim3(1024), 256, 0, stream>>>(qhh, khh, lbt, att);
  k_out      <<<dim3(512), 512, 0, stream>>>(xc, wtp, out, proj_b, q, a2, b2);
}

// Round 10
// 356.579 us; speedup vs baseline: 1.0624x; 1.0624x over previous
//
#include <hip/hip_runtime.h>
#include <stdint.h>

typedef unsigned short u16;
typedef u16   u16x4v __attribute__((ext_vector_type(4)));
typedef u16   u16x8v __attribute__((ext_vector_type(8)));
typedef short s16x8v __attribute__((ext_vector_type(8)));
typedef float f32x4v __attribute__((ext_vector_type(4)));

#define DEV static __device__ __forceinline__

// fp32 -> bf16 round-to-nearest-even (scalar)
DEV u16 f2bf(float f){
  union { float f; unsigned u; } v; v.f = f;
  unsigned r = v.u + 0x7FFFu + ((v.u >> 16) & 1u);
  return (u16)(r >> 16);
}

DEV f32x4v mfma16(s16x8v a, s16x8v b, f32x4v c){
  return __builtin_amdgcn_mfma_f32_16x16x32_bf16(a, b, c, 0, 0, 0);
}

// ---------------------------------------------------------------------------
// k_wall: all weight prep in one launch. (unchanged — passed)
__global__ __launch_bounds__(256) void k_wall(const float* __restrict__ w_qs,
                                              const float* __restrict__ w_ks,
                                              const float* __restrict__ w_vs,
                                              const float* __restrict__ proj_w,
                                              u16* __restrict__ wt, u16* __restrict__ wtp,
                                              float qscale){
  int gid = blockIdx.x;
  int tsel = gid >> 10;
  int e = (gid & 1023) * 256 + threadIdx.x;
  if(tsel == 3){
    wtp[e] = f2bf(proj_w[e]);
  } else {
    const float* w = tsel == 0 ? w_qs : (tsel == 1 ? w_ks : w_vs);
    float sc = tsel == 0 ? qscale : 1.0f;
    int n = e >> 9, d = e & 511;
    int h = n >> 6, kk = n & 63;
    wt[tsel * 262144 + n * 512 + d] = f2bf(w[h * 32768 + d * 64 + kk] * sc);
  }
}

// ---------------------------------------------------------------------------
// Fused QKV projection (unchanged — passed).
__global__ __launch_bounds__(256) void k_qkv(const float* __restrict__ Q,
                                             const float* __restrict__ K,
                                             const float* __restrict__ V,
                                             const u16* __restrict__ Wt,
                                             u16* __restrict__ qhh, u16* __restrict__ khh,
                                             u16* __restrict__ vtt){
  __shared__ __align__(16) u16 Xs[32 * 520];
  const int t = threadIdx.x;
  const int lane = t & 63, w = t >> 6;
  const int g = lane >> 4, li = lane & 15;
  const int i0 = blockIdx.x * 32;
  const int y = blockIdx.y;
  const int tsel = y >> 1;
  const float* X = tsel == 0 ? Q : (tsel == 1 ? K : V);
  const int n0 = (y & 1) * 256 + w * 64;

  #pragma unroll
  for(int it = 0; it < 16; ++it){
    int s = it * 256 + t, row = s >> 7, c4 = s & 127;
    f32x4v xv = *(const f32x4v*)(X + (size_t)(i0 + row) * 512 + c4 * 4);
    u16x4v bv; bv[0]=f2bf(xv[0]); bv[1]=f2bf(xv[1]); bv[2]=f2bf(xv[2]); bv[3]=f2bf(xv[3]);
    *(u16x4v*)(Xs + row * 520 + c4 * 4) = bv;
  }
  __syncthreads();

  const int wbase = tsel * 512 + n0;
  const u16* wp0 = Wt + (size_t)(wbase +  0 + li) * 512 + g * 8;
  const u16* wp1 = Wt + (size_t)(wbase + 16 + li) * 512 + g * 8;
  const u16* wp2 = Wt + (size_t)(wbase + 32 + li) * 512 + g * 8;
  const u16* wp3 = Wt + (size_t)(wbase + 48 + li) * 512 + g * 8;

#define LOADW(S, c) { \
  S##0 = *(const s16x8v*)(wp0 + (c) * 32); \
  S##1 = *(const s16x8v*)(wp1 + (c) * 32); \
  S##2 = *(const s16x8v*)(wp2 + (c) * 32); \
  S##3 = *(const s16x8v*)(wp3 + (c) * 32); }
#define COMPW(S, c) { \
  int k0 = (c) * 32 + g * 8; \
  s16x8v a0 = *(const s16x8v*)(Xs + li * 520 + k0); \
  s16x8v a1 = *(const s16x8v*)(Xs + (16 + li) * 520 + k0); \
  acc[0][0] = mfma16(a0, S##0, acc[0][0]); acc[1][0] = mfma16(a1, S##0, acc[1][0]); \
  acc[0][1] = mfma16(a0, S##1, acc[0][1]); acc[1][1] = mfma16(a1, S##1, acc[1][1]); \
  acc[0][2] = mfma16(a0, S##2, acc[0][2]); acc[1][2] = mfma16(a1, S##2, acc[1][2]); \
  acc[0][3] = mfma16(a0, S##3, acc[0][3]); acc[1][3] = mfma16(a1, S##3, acc[1][3]); }

  f32x4v acc[2][4] = {};
  s16x8v wA0, wA1, wA2, wA3, wB0, wB1, wB2, wB3;
  LOADW(wA, 0);
  #pragma unroll
  for(int c = 0; c < 16; c += 2){
    LOADW(wB, c + 1);
    COMPW(wA, c);
    if(c + 2 < 16) LOADW(wA, c + 2);
    COMPW(wB, c + 1);
  }
#undef LOADW
#undef COMPW

  if(tsel < 2){
    u16* Y = tsel == 0 ? qhh : khh;
    #pragma unroll
    for(int rg = 0; rg < 2; ++rg)
      #pragma unroll
      for(int j = 0; j < 4; ++j){
        int n = n0 + j * 16 + li, h = n >> 6, dk = n & 63;
        #pragma unroll
        for(int r = 0; r < 4; ++r){
          int i = i0 + rg * 16 + g * 4 + r, bb = i >> 11, m = i & 2047;
          Y[((size_t)(h * 4 + bb) * 2048 + m) * 64 + dk] = f2bf(acc[rg][j][r]);
        }
      }
  } else {
    #pragma unroll
    for(int rg = 0; rg < 2; ++rg)
      #pragma unroll
      for(int j = 0; j < 4; ++j){
        int n = n0 + j * 16 + li;
        u16x4v pk;
        #pragma unroll
        for(int r = 0; r < 4; ++r) pk[r] = f2bf(acc[rg][j][r]);
        *(u16x4v*)(vtt + (size_t)n * 8192 + i0 + g * 8 + rg * 4) = pk;
      }
  }
}

// ---------------------------------------------------------------------------
// Attention, m-split: block = 4 waves = 2 q-subtiles (32 rows) x 2 m-halves
// (1024 keys). K and V 2-deep double-buffered. ATT stores are PLAIN f32x4
// (L2-allocating): nontemporal's slow store-ack serialized the in-order
// vmcnt FIFO — every load-wait inherited HBM-ack latency of older stores.

#define LOADK(B, ht) { \
  const u16* _p = kp + (size_t)(ht) * 2048; \
  B##0 = *(const s16x8v*)(_p); \
  B##1 = *(const s16x8v*)(_p + 32); \
  B##2 = *(const s16x8v*)(_p + 1024); \
  B##3 = *(const s16x8v*)(_p + 1056); }

#define STEPA(B) { \
  f32x4v z0 = {}, z1 = {}; \
  z0 = mfma16(B##0, bq00, z0); z0 = mfma16(B##1, bq01, z0); \
  z1 = mfma16(B##2, bq00, z1); z1 = mfma16(B##3, bq01, z1); \
  _Pragma("unroll") for(int r = 0; r < 4; ++r){ s00[r] += exp2f(z0[r]); s01[r] += exp2f(z1[r]); } \
  f32x4v y0 = {}, y1 = {}; \
  y0 = mfma16(B##0, bq10, y0); y0 = mfma16(B##1, bq11, y0); \
  y1 = mfma16(B##2, bq10, y1); y1 = mfma16(B##3, bq11, y1); \
  _Pragma("unroll") for(int r = 0; r < 4; ++r){ s10[r] += exp2f(y0[r]); s11[r] += exp2f(y1[r]); } }

#define LOADV(B, ht) { \
  const u16* _p = vp + (ht) * 32; \
  B##0 = *(const s16x8v*)(_p); \
  B##1 = *(const s16x8v*)(_p + 131072); \
  B##2 = *(const s16x8v*)(_p + 262144); \
  B##3 = *(const s16x8v*)(_p + 393216); }

#define QS_HALF(KB, VB, bqa, bqb, lb, qs_, ht) { \
  f32x4v z0 = {}, z1 = {}; \
  z0 = mfma16(KB##0, bqa, z0); z0 = mfma16(KB##1, bqb, z0); \
  z1 = mfma16(KB##2, bqa, z1); z1 = mfma16(KB##3, bqb, z1); \
  f32x4v p0, p1; \
  _Pragma("unroll") for(int r = 0; r < 4; ++r){ p0[r] = exp2f(z0[r] + lb); p1[r] = exp2f(z1[r] + lb); } \
  float* _ab = attb + (size_t)((qs_) * 16 + li) * 2048 + (ht) * 32 + g * 4; \
  *(f32x4v*)(_ab) = p0; \
  *(f32x4v*)(_ab + 16) = p1; \
  union { u16 hh[8]; s16x8v v; } _u; \
  _Pragma("unroll") for(int r = 0; r < 4; ++r){ _u.hh[r] = f2bf(p0[r]); _u.hh[4 + r] = f2bf(p1[r]); } \
  acc##qs_##0 = mfma16(_u.v, VB##0, acc##qs_##0); \
  acc##qs_##1 = mfma16(_u.v, VB##1, acc##qs_##1); \
  acc##qs_##2 = mfma16(_u.v, VB##2, acc##qs_##2); \
  acc##qs_##3 = mfma16(_u.v, VB##3, acc##qs_##3); }

#define STEPB(KB, VB, ht) { \
  QS_HALF(KB, VB, bq00, bq01, lb0, 0, ht); \
  QS_HALF(KB, VB, bq10, bq11, lb1, 1, ht); }

__global__ __launch_bounds__(256, 3) void k_attn(const u16* __restrict__ QHH, const u16* __restrict__ KHH,
                                                 const u16* __restrict__ VTT,
                                                 u16* __restrict__ XC, float* __restrict__ ATT){
  __shared__ float Lp[2][2][32];        // [qs][mh][row]
  __shared__ float AccS[2][32][64];     // [qs][elem][lane]  = 16 KB
  const int t = threadIdx.x, lane = t & 63, w = t >> 6;
  const int g = lane >> 4, li = lane & 15;
  const int qs = w >> 1, mh = w & 1;
  // XCD swizzle: 32 q-tiles of one hb on one XCD; 4 hb per XCD
  const int gid = blockIdx.x;                // 0..1023
  const int xcd = gid & 7, rem = gid >> 3;   // rem 0..127
  const int qt = rem & 31;
  const int hb = xcd * 4 + (rem >> 5);
  const int h = hb >> 2, b = hb & 3;
  const size_t base_hb = (size_t)hb * 2048;
  const int qbase = qt * 64 + qs * 32;

  s16x8v bq00, bq01, bq10, bq11;
  {
    const u16* qp0 = QHH + (base_hb + qbase + li) * 64 + g * 8;
    const u16* qp1 = QHH + (base_hb + qbase + 16 + li) * 64 + g * 8;
    bq00 = *(const s16x8v*)(qp0); bq01 = *(const s16x8v*)(qp0 + 32);
    bq10 = *(const s16x8v*)(qp1); bq11 = *(const s16x8v*)(qp1 + 32);
  }
  // wave-local K/V/ATT bases include the m-half offset (32 ht-steps each)
  const u16* kp = KHH + (base_hb + li) * 64 + g * 8 + (size_t)mh * 65536;
  const u16* vp = VTT + (size_t)(h * 64 + li) * 8192 + b * 2048 + g * 8 + mh * 1024;
  float* attb = ATT + (base_hb + qbase) * 2048 + mh * 1024;

  // ---- pass A: per-lane exp2 partial sums over this wave's 1024 keys ----
  f32x4v s00 = {}, s01 = {}, s10 = {}, s11 = {};
  {
    s16x8v kA0, kA1, kA2, kA3, kB0, kB1, kB2, kB3;
    LOADK(kA, 0);
    for(int ht = 0; ht < 30; ht += 2){
      LOADK(kB, ht + 1);
      STEPA(kA);
      LOADK(kA, ht + 2);
      STEPA(kB);
    }
    LOADK(kB, 31);
    STEPA(kA);
    STEPA(kB);
  }
  float l0 = (s00[0]+s00[1]+s00[2]+s00[3]) + (s01[0]+s01[1]+s01[2]+s01[3]);
  float l1 = (s10[0]+s10[1]+s10[2]+s10[3]) + (s11[0]+s11[1]+s11[2]+s11[3]);
  l0 += __shfl_xor(l0, 16, 64); l0 += __shfl_xor(l0, 32, 64);
  l1 += __shfl_xor(l1, 16, 64); l1 += __shfl_xor(l1, 32, 64);
  if(lane < 16){ Lp[qs][mh][li] = l0; Lp[qs][mh][16 + li] = l1; }
  __syncthreads();
  // P = exp2(z - log2(l_total)) ; fold normalization into the exponent
  const float lb0 = -__log2f(Lp[qs][0][li]      + Lp[qs][1][li]);
  const float lb1 = -__log2f(Lp[qs][0][16 + li] + Lp[qs][1][16 + li]);

  // ---- pass B over this wave's 1024 keys ----
  f32x4v acc00 = {}, acc01 = {}, acc02 = {}, acc03 = {};
  f32x4v acc10 = {}, acc11 = {}, acc12 = {}, acc13 = {};
  {
    s16x8v kA0, kA1, kA2, kA3, kB0, kB1, kB2, kB3;
    s16x8v vA0, vA1, vA2, vA3, vB0, vB1, vB2, vB3;
    LOADK(kA, 0); LOADV(vA, 0);
    for(int ht = 0; ht < 30; ht += 2){
      LOADK(kB, ht + 1); LOADV(vB, ht + 1);
      STEPB(kA, vA, ht);
      LOADK(kA, ht + 2); LOADV(vA, ht + 2);
      STEPB(kB, vB, ht + 1);
    }
    LOADK(kB, 31); LOADV(vB, 31);
    STEPB(kA, vA, 30);
    STEPB(kB, vB, 31);
  }

  // ---- combine PV partials across m-halves ----
  if(mh == 1){
    #pragma unroll
    for(int r = 0; r < 4; ++r){
      AccS[qs][ 0 + r][lane] = acc00[r];
      AccS[qs][ 4 + r][lane] = acc01[r];
      AccS[qs][ 8 + r][lane] = acc02[r];
      AccS[qs][12 + r][lane] = acc03[r];
      AccS[qs][16 + r][lane] = acc10[r];
      AccS[qs][20 + r][lane] = acc11[r];
      AccS[qs][24 + r][lane] = acc12[r];
      AccS[qs][28 + r][lane] = acc13[r];
    }
  }
  __syncthreads();
  if(mh == 0){
    #pragma unroll
    for(int r = 0; r < 4; ++r){
      acc00[r] += AccS[qs][ 0 + r][lane];
      acc01[r] += AccS[qs][ 4 + r][lane];
      acc02[r] += AccS[qs][ 8 + r][lane];
      acc03[r] += AccS[qs][12 + r][lane];
      acc10[r] += AccS[qs][16 + r][lane];
      acc11[r] += AccS[qs][20 + r][lane];
      acc12[r] += AccS[qs][24 + r][lane];
      acc13[r] += AccS[qs][28 + r][lane];
    }
    #pragma unroll
    for(int r = 0; r < 4; ++r){
      int row0 = qbase + g * 4 + r;
      int row1 = qbase + 16 + g * 4 + r;
      u16* x0 = XC + (size_t)(b * 2048 + row0) * 512 + h * 64 + li;
      u16* x1 = XC + (size_t)(b * 2048 + row1) * 512 + h * 64 + li;
      x0[0]  = f2bf(acc00[r]); x0[16] = f2bf(acc01[r]); x0[32] = f2bf(acc02[r]); x0[48] = f2bf(acc03[r]);
      x1[0]  = f2bf(acc10[r]); x1[16] = f2bf(acc11[r]); x1[32] = f2bf(acc12[r]); x1[48] = f2bf(acc13[r]);
    }
  }
}

// ---------------------------------------------------------------------------
// Out-projection + bias + residual + LayerNorm (unchanged — passed).
__global__ __launch_bounds__(512) void k_out(const u16* __restrict__ Xb,
                                             const u16* __restrict__ Wtp,
                                             float* __restrict__ Yf,
                                             const float* __restrict__ bias,
                                             const float* __restrict__ resid,
                                             const float* __restrict__ a2,
                                             const float* __restrict__ b2){
  __shared__ __align__(16) u16 Xs[16 * 520];
  __shared__ float sred[8][16], sqred[8][16], muL[16], rsL[16];
  const int t = threadIdx.x;
  const int lane = t & 63, w = t >> 6;
  const int g = lane >> 4, li = lane & 15;
  const int i0 = blockIdx.x * 16;
  const int n0 = w * 64;

  #pragma unroll
  for(int it = 0; it < 2; ++it){
    int s = it * 512 + t, row = s >> 6, c8 = s & 63;
    u16x8v xv = *(const u16x8v*)(Xb + (size_t)(i0 + row) * 512 + c8 * 8);
    *(u16x8v*)(Xs + row * 520 + c8 * 8) = xv;
  }
  __syncthreads();

  const u16* wp0 = Wtp + (size_t)(n0 +  0 + li) * 512 + g * 8;
  const u16* wp1 = Wtp + (size_t)(n0 + 16 + li) * 512 + g * 8;
  const u16* wp2 = Wtp + (size_t)(n0 + 32 + li) * 512 + g * 8;
  const u16* wp3 = Wtp + (size_t)(n0 + 48 + li) * 512 + g * 8;

#define LOADW(S, c) { \
  S##0 = *(const s16x8v*)(wp0 + (c) * 32); \
  S##1 = *(const s16x8v*)(wp1 + (c) * 32); \
  S##2 = *(const s16x8v*)(wp2 + (c) * 32); \
  S##3 = *(const s16x8v*)(wp3 + (c) * 32); }
#define COMPW(S, c) { \
  int k0 = (c) * 32 + g * 8; \
  s16x8v a0 = *(const s16x8v*)(Xs + li * 520 + k0); \
  acc[0] = mfma16(a0, S##0, acc[0]); \
  acc[1] = mfma16(a0, S##1, acc[1]); \
  acc[2] = mfma16(a0, S##2, acc[2]); \
  acc[3] = mfma16(a0, S##3, acc[3]); }

  f32x4v acc[4] = {};
  s16x8v wA0, wA1, wA2, wA3, wB0, wB1, wB2, wB3;
  LOADW(wA, 0);
  #pragma unroll
  for(int c = 0; c < 16; c += 2){
    LOADW(wB, c + 1);
    COMPW(wA, c);
    if(c + 2 < 16) LOADW(wA, c + 2);
    COMPW(wB, c + 1);
  }
#undef LOADW
#undef COMPW

  float zres[4][4];
  #pragma unroll
  for(int j = 0; j < 4; ++j){
    int n = n0 + j * 16 + li;
    float bv = bias[n];
    #pragma unroll
    for(int r = 0; r < 4; ++r){
      int i = i0 + g * 4 + r;
      zres[j][r] = acc[j][r] + bv + resid[(size_t)i * 512 + n];
    }
  }
  #pragma unroll
  for(int r = 0; r < 4; ++r){
    float S = 0.f, SQ = 0.f;
    #pragma unroll
    for(int j = 0; j < 4; ++j){ float zz = zres[j][r]; S += zz; SQ += zz * zz; }
    #pragma unroll
    for(int off = 1; off < 16; off <<= 1){ S += __shfl_xor(S, off, 16); SQ += __shfl_xor(SQ, off, 16); }
    if(li == 0){ sred[w][g * 4 + r] = S; sqred[w][g * 4 + r] = SQ; }
  }
  __syncthreads();
  if(t < 16){
    float S = 0.f, SQ = 0.f;
    #pragma unroll
    for(int ww = 0; ww < 8; ++ww){ S += sred[ww][t]; SQ += sqred[ww][t]; }
    float mu = S * (1.0f / 512.0f);
    float var = (SQ - 512.0f * mu * mu) * (1.0f / 511.0f);
    muL[t] = mu;
    rsL[t] = 1.0f / (sqrtf(fmaxf(var, 0.0f)) + 1e-3f);
  }
  __syncthreads();
  #pragma unroll
  for(int r = 0; r < 4; ++r){
    int rloc = g * 4 + r;
    float mu = muL[rloc], rs = rsL[rloc];
    size_t ib = (size_t)(i0 + rloc) * 512;
    #pragma unroll
    for(int j = 0; j < 4; ++j){
      int n = n0 + j * 16 + li;
      Yf[ib + n] = (zres[j][r] - mu) * rs * a2[n] + b2[n];
    }
  }
}

// ---------------------------------------------------------------------------
extern "C" void kernel_launch(void* const* d_in, const int* in_sizes, int n_in,
                              void* d_out, int out_size, void* d_ws, size_t ws_size,
                              hipStream_t stream){
  const float* q      = (const float*)d_in[0];
  const float* k      = (const float*)d_in[1];
  const float* v      = (const float*)d_in[2];
  const float* w_qs   = (const float*)d_in[3];
  const float* w_ks   = (const float*)d_in[4];
  const float* w_vs   = (const float*)d_in[5];
  const float* proj_w = (const float*)d_in[6];
  const float* proj_b = (const float*)d_in[7];
  const float* a2     = (const float*)d_in[8];
  const float* b2     = (const float*)d_in[9];

  char* ws = (char*)d_ws;
  u16* wt    = (u16*)(ws);                       // 3 x 512KB (q-weights pre-scaled)
  u16* wtp   = (u16*)(ws + 1572864);             // 512KB proj_w bf16
  u16* qhh   = (u16*)(ws + 2097152);             // 8 MB head-major
  u16* khh   = (u16*)(ws + 10485760);            // 8 MB head-major
  u16* vtt   = (u16*)(ws + 18874368);            // 8 MB [n][perm(i)]
  u16* xc    = (u16*)(ws + 27262976);            // 8 MB [i][512]

  float* out = (float*)d_out;                    // (4,2048,512) fp32
  float* att = out + 4194304;                    // (32,2048,2048) fp32

  // fold 1/sqrt(512) * log2(e) into the Q projection weights
  const float qscale = 0.06375872032774575f;

  k_wall<<<dim3(4096), 256, 0, stream>>>(w_qs, w_ks, w_vs, proj_w, wt, wtp, qscale);
  k_qkv <<<dim3(256, 6), 256, 0, stream>>>(q, k, v, wt, qhh, khh, vtt);
  k_attn<<<dim3(1024), 256, 0, stream>>>(qhh, khh, vtt, xc, att);
  k_out <<<dim3(512), 512, 0, stream>>>(xc, wtp, out, proj_b, q, a2, b2);
}

// Round 11
// 291.408 us; speedup vs baseline: 1.3000x; 1.2236x over previous
//
#include <hip/hip_runtime.h>
#include <stdint.h>

typedef unsigned short u16;
typedef u16   u16x4v __attribute__((ext_vector_type(4)));
typedef u16   u16x8v __attribute__((ext_vector_type(8)));
typedef short s16x8v __attribute__((ext_vector_type(8)));
typedef float f32x4v __attribute__((ext_vector_type(4)));

#define DEV static __device__ __forceinline__

// fp32 -> bf16 round-to-nearest-even (scalar)
DEV u16 f2bf(float f){
  union { float f; unsigned u; } v; v.f = f;
  unsigned r = v.u + 0x7FFFu + ((v.u >> 16) & 1u);
  return (u16)(r >> 16);
}

DEV f32x4v mfma16(s16x8v a, s16x8v b, f32x4v c){
  return __builtin_amdgcn_mfma_f32_16x16x32_bf16(a, b, c, 0, 0, 0);
}

// ---------------------------------------------------------------------------
// k_wall: all weight prep in one launch. (unchanged — passed)
__global__ __launch_bounds__(256) void k_wall(const float* __restrict__ w_qs,
                                              const float* __restrict__ w_ks,
                                              const float* __restrict__ w_vs,
                                              const float* __restrict__ proj_w,
                                              u16* __restrict__ wt, u16* __restrict__ wtp,
                                              float qscale){
  int gid = blockIdx.x;
  int tsel = gid >> 10;
  int e = (gid & 1023) * 256 + threadIdx.x;
  if(tsel == 3){
    wtp[e] = f2bf(proj_w[e]);
  } else {
    const float* w = tsel == 0 ? w_qs : (tsel == 1 ? w_ks : w_vs);
    float sc = tsel == 0 ? qscale : 1.0f;
    int n = e >> 9, d = e & 511;
    int h = n >> 6, kk = n & 63;
    wt[tsel * 262144 + n * 512 + d] = f2bf(w[h * 32768 + d * 64 + kk] * sc);
  }
}

// ---------------------------------------------------------------------------
// Fused QKV projection (unchanged — passed).
__global__ __launch_bounds__(256) void k_qkv(const float* __restrict__ Q,
                                             const float* __restrict__ K,
                                             const float* __restrict__ V,
                                             const u16* __restrict__ Wt,
                                             u16* __restrict__ qhh, u16* __restrict__ khh,
                                             u16* __restrict__ vtt){
  __shared__ __align__(16) u16 Xs[32 * 520];
  const int t = threadIdx.x;
  const int lane = t & 63, w = t >> 6;
  const int g = lane >> 4, li = lane & 15;
  const int i0 = blockIdx.x * 32;
  const int y = blockIdx.y;
  const int tsel = y >> 1;
  const float* X = tsel == 0 ? Q : (tsel == 1 ? K : V);
  const int n0 = (y & 1) * 256 + w * 64;

  #pragma unroll
  for(int it = 0; it < 16; ++it){
    int s = it * 256 + t, row = s >> 7, c4 = s & 127;
    f32x4v xv = *(const f32x4v*)(X + (size_t)(i0 + row) * 512 + c4 * 4);
    u16x4v bv; bv[0]=f2bf(xv[0]); bv[1]=f2bf(xv[1]); bv[2]=f2bf(xv[2]); bv[3]=f2bf(xv[3]);
    *(u16x4v*)(Xs + row * 520 + c4 * 4) = bv;
  }
  __syncthreads();

  const int wbase = tsel * 512 + n0;
  const u16* wp0 = Wt + (size_t)(wbase +  0 + li) * 512 + g * 8;
  const u16* wp1 = Wt + (size_t)(wbase + 16 + li) * 512 + g * 8;
  const u16* wp2 = Wt + (size_t)(wbase + 32 + li) * 512 + g * 8;
  const u16* wp3 = Wt + (size_t)(wbase + 48 + li) * 512 + g * 8;

#define LOADW(S, c) { \
  S##0 = *(const s16x8v*)(wp0 + (c) * 32); \
  S##1 = *(const s16x8v*)(wp1 + (c) * 32); \
  S##2 = *(const s16x8v*)(wp2 + (c) * 32); \
  S##3 = *(const s16x8v*)(wp3 + (c) * 32); }
#define COMPW(S, c) { \
  int k0 = (c) * 32 + g * 8; \
  s16x8v a0 = *(const s16x8v*)(Xs + li * 520 + k0); \
  s16x8v a1 = *(const s16x8v*)(Xs + (16 + li) * 520 + k0); \
  acc[0][0] = mfma16(a0, S##0, acc[0][0]); acc[1][0] = mfma16(a1, S##0, acc[1][0]); \
  acc[0][1] = mfma16(a0, S##1, acc[0][1]); acc[1][1] = mfma16(a1, S##1, acc[1][1]); \
  acc[0][2] = mfma16(a0, S##2, acc[0][2]); acc[1][2] = mfma16(a1, S##2, acc[1][2]); \
  acc[0][3] = mfma16(a0, S##3, acc[0][3]); acc[1][3] = mfma16(a1, S##3, acc[1][3]); }

  f32x4v acc[2][4] = {};
  s16x8v wA0, wA1, wA2, wA3, wB0, wB1, wB2, wB3;
  LOADW(wA, 0);
  #pragma unroll
  for(int c = 0; c < 16; c += 2){
    LOADW(wB, c + 1);
    COMPW(wA, c);
    if(c + 2 < 16) LOADW(wA, c + 2);
    COMPW(wB, c + 1);
  }
#undef LOADW
#undef COMPW

  if(tsel < 2){
    u16* Y = tsel == 0 ? qhh : khh;
    #pragma unroll
    for(int rg = 0; rg < 2; ++rg)
      #pragma unroll
      for(int j = 0; j < 4; ++j){
        int n = n0 + j * 16 + li, h = n >> 6, dk = n & 63;
        #pragma unroll
        for(int r = 0; r < 4; ++r){
          int i = i0 + rg * 16 + g * 4 + r, bb = i >> 11, m = i & 2047;
          Y[((size_t)(h * 4 + bb) * 2048 + m) * 64 + dk] = f2bf(acc[rg][j][r]);
        }
      }
  } else {
    #pragma unroll
    for(int rg = 0; rg < 2; ++rg)
      #pragma unroll
      for(int j = 0; j < 4; ++j){
        int n = n0 + j * 16 + li;
        u16x4v pk;
        #pragma unroll
        for(int r = 0; r < 4; ++r) pk[r] = f2bf(acc[rg][j][r]);
        *(u16x4v*)(vtt + (size_t)n * 8192 + i0 + g * 8 + rg * 4) = pk;
      }
  }
}

// ---------------------------------------------------------------------------
// Attention, m-split (r8 base). ATT stores now go through a per-wave 2KB LDS
// tile (XOR-swizzled quads, conflict-free, same-wave so no barrier) and are
// emitted as 8 FULL 128B lines per store instruction instead of 16 half-lines.

#define LOADK(B, ht) { \
  const u16* _p = kp + (size_t)(ht) * 2048; \
  B##0 = *(const s16x8v*)(_p); \
  B##1 = *(const s16x8v*)(_p + 32); \
  B##2 = *(const s16x8v*)(_p + 1024); \
  B##3 = *(const s16x8v*)(_p + 1056); }

#define STEPA(B) { \
  f32x4v z0 = {}, z1 = {}; \
  z0 = mfma16(B##0, bq00, z0); z0 = mfma16(B##1, bq01, z0); \
  z1 = mfma16(B##2, bq00, z1); z1 = mfma16(B##3, bq01, z1); \
  _Pragma("unroll") for(int r = 0; r < 4; ++r){ s00[r] += exp2f(z0[r]); s01[r] += exp2f(z1[r]); } \
  f32x4v y0 = {}, y1 = {}; \
  y0 = mfma16(B##0, bq10, y0); y0 = mfma16(B##1, bq11, y0); \
  y1 = mfma16(B##2, bq10, y1); y1 = mfma16(B##3, bq11, y1); \
  _Pragma("unroll") for(int r = 0; r < 4; ++r){ s10[r] += exp2f(y0[r]); s11[r] += exp2f(y1[r]); } }

#define LOADV(B, ht) { \
  const u16* _p = vp + (ht) * 32; \
  B##0 = *(const s16x8v*)(_p); \
  B##1 = *(const s16x8v*)(_p + 131072); \
  B##2 = *(const s16x8v*)(_p + 262144); \
  B##3 = *(const s16x8v*)(_p + 393216); }

// Swizzled quad offset inside the wave tile: row*32 + ((quad ^ (row&7))*4)
#define QS_HALF(KB, VB, bqa, bqb, lb, qs_, ht) { \
  f32x4v z0 = {}, z1 = {}; \
  z0 = mfma16(KB##0, bqa, z0); z0 = mfma16(KB##1, bqb, z0); \
  z1 = mfma16(KB##2, bqa, z1); z1 = mfma16(KB##3, bqb, z1); \
  f32x4v p0, p1; \
  _Pragma("unroll") for(int r = 0; r < 4; ++r){ p0[r] = exp2f(z0[r] + lb); p1[r] = exp2f(z1[r] + lb); } \
  *(f32x4v*)(Pt + li * 32 + (((g)     ^ (li & 7)) << 2)) = p0; \
  *(f32x4v*)(Pt + li * 32 + (((g + 4) ^ (li & 7)) << 2)) = p1; \
  f32x4v q0 = *(const f32x4v*)(Pt + rr * 32 + ((cc ^ rr) << 2)); \
  f32x4v q1 = *(const f32x4v*)(Pt + (8 + rr) * 32 + ((cc ^ rr) << 2)); \
  float* _ab = attb + (size_t)((qs_) * 16 + rr) * 2048 + (ht) * 32 + cc * 4; \
  __builtin_nontemporal_store(q0, (f32x4v*)(_ab)); \
  __builtin_nontemporal_store(q1, (f32x4v*)(_ab + 8 * 2048)); \
  union { u16 hh[8]; s16x8v v; } _u; \
  _Pragma("unroll") for(int r = 0; r < 4; ++r){ _u.hh[r] = f2bf(p0[r]); _u.hh[4 + r] = f2bf(p1[r]); } \
  acc##qs_##0 = mfma16(_u.v, VB##0, acc##qs_##0); \
  acc##qs_##1 = mfma16(_u.v, VB##1, acc##qs_##1); \
  acc##qs_##2 = mfma16(_u.v, VB##2, acc##qs_##2); \
  acc##qs_##3 = mfma16(_u.v, VB##3, acc##qs_##3); }

#define STEPB(KB, VB, ht) { \
  QS_HALF(KB, VB, bq00, bq01, lb0, 0, ht); \
  QS_HALF(KB, VB, bq10, bq11, lb1, 1, ht); }

__global__ __launch_bounds__(256, 3) void k_attn(const u16* __restrict__ QHH, const u16* __restrict__ KHH,
                                                 const u16* __restrict__ VTT,
                                                 u16* __restrict__ XC, float* __restrict__ ATT){
  __shared__ float Lp[2][2][32];        // [qs][mh][row]
  __shared__ float AccS[2][32][64];     // [qs][elem][lane]  = 16 KB
  __shared__ __align__(16) float Pt4[4][512];  // per-wave P transpose tile, 8 KB
  const int t = threadIdx.x, lane = t & 63, w = t >> 6;
  const int g = lane >> 4, li = lane & 15;
  const int rr = lane >> 3, cc = lane & 7;     // store-side row/col-quad
  const int qs = w >> 1, mh = w & 1;
  float* Pt = Pt4[w];
  // XCD swizzle: 32 q-tiles of one hb on one XCD; 4 hb per XCD
  const int gid = blockIdx.x;                // 0..1023
  const int xcd = gid & 7, rem = gid >> 3;   // rem 0..127
  const int qt = rem & 31;
  const int hb = xcd * 4 + (rem >> 5);
  const int h = hb >> 2, b = hb & 3;
  const size_t base_hb = (size_t)hb * 2048;
  const int qbase = qt * 64 + qs * 32;

  s16x8v bq00, bq01, bq10, bq11;
  {
    const u16* qp0 = QHH + (base_hb + qbase + li) * 64 + g * 8;
    const u16* qp1 = QHH + (base_hb + qbase + 16 + li) * 64 + g * 8;
    bq00 = *(const s16x8v*)(qp0); bq01 = *(const s16x8v*)(qp0 + 32);
    bq10 = *(const s16x8v*)(qp1); bq11 = *(const s16x8v*)(qp1 + 32);
  }
  // wave-local K/V/ATT bases include the m-half offset (32 ht-steps each)
  const u16* kp = KHH + (base_hb + li) * 64 + g * 8 + (size_t)mh * 65536;
  const u16* vp = VTT + (size_t)(h * 64 + li) * 8192 + b * 2048 + g * 8 + mh * 1024;
  float* attb = ATT + (base_hb + qbase) * 2048 + mh * 1024;

  // ---- pass A: per-lane exp2 partial sums over this wave's 1024 keys ----
  f32x4v s00 = {}, s01 = {}, s10 = {}, s11 = {};
  {
    s16x8v kA0, kA1, kA2, kA3, kB0, kB1, kB2, kB3;
    LOADK(kA, 0);
    for(int ht = 0; ht < 30; ht += 2){
      LOADK(kB, ht + 1);
      STEPA(kA);
      LOADK(kA, ht + 2);
      STEPA(kB);
    }
    LOADK(kB, 31);
    STEPA(kA);
    STEPA(kB);
  }
  float l0 = (s00[0]+s00[1]+s00[2]+s00[3]) + (s01[0]+s01[1]+s01[2]+s01[3]);
  float l1 = (s10[0]+s10[1]+s10[2]+s10[3]) + (s11[0]+s11[1]+s11[2]+s11[3]);
  l0 += __shfl_xor(l0, 16, 64); l0 += __shfl_xor(l0, 32, 64);
  l1 += __shfl_xor(l1, 16, 64); l1 += __shfl_xor(l1, 32, 64);
  if(lane < 16){ Lp[qs][mh][li] = l0; Lp[qs][mh][16 + li] = l1; }
  __syncthreads();
  // P = exp2(z - log2(l_total)) ; fold normalization into the exponent
  const float lb0 = -__log2f(Lp[qs][0][li]      + Lp[qs][1][li]);
  const float lb1 = -__log2f(Lp[qs][0][16 + li] + Lp[qs][1][16 + li]);

  // ---- pass B over this wave's 1024 keys ----
  f32x4v acc00 = {}, acc01 = {}, acc02 = {}, acc03 = {};
  f32x4v acc10 = {}, acc11 = {}, acc12 = {}, acc13 = {};
  {
    s16x8v kA0, kA1, kA2, kA3, kB0, kB1, kB2, kB3;
    s16x8v vA0, vA1, vA2, vA3, vB0, vB1, vB2, vB3;
    LOADK(kA, 0); LOADV(vA, 0);
    for(int ht = 0; ht < 30; ht += 2){
      LOADK(kB, ht + 1); LOADV(vB, ht + 1);
      STEPB(kA, vA, ht);
      LOADK(kA, ht + 2); LOADV(vA, ht + 2);
      STEPB(kB, vB, ht + 1);
    }
    LOADK(kB, 31); LOADV(vB, 31);
    STEPB(kA, vA, 30);
    STEPB(kB, vB, 31);
  }

  // ---- combine PV partials across m-halves ----
  if(mh == 1){
    #pragma unroll
    for(int r = 0; r < 4; ++r){
      AccS[qs][ 0 + r][lane] = acc00[r];
      AccS[qs][ 4 + r][lane] = acc01[r];
      AccS[qs][ 8 + r][lane] = acc02[r];
      AccS[qs][12 + r][lane] = acc03[r];
      AccS[qs][16 + r][lane] = acc10[r];
      AccS[qs][20 + r][lane] = acc11[r];
      AccS[qs][24 + r][lane] = acc12[r];
      AccS[qs][28 + r][lane] = acc13[r];
    }
  }
  __syncthreads();
  if(mh == 0){
    #pragma unroll
    for(int r = 0; r < 4; ++r){
      acc00[r] += AccS[qs][ 0 + r][lane];
      acc01[r] += AccS[qs][ 4 + r][lane];
      acc02[r] += AccS[qs][ 8 + r][lane];
      acc03[r] += AccS[qs][12 + r][lane];
      acc10[r] += AccS[qs][16 + r][lane];
      acc11[r] += AccS[qs][20 + r][lane];
      acc12[r] += AccS[qs][24 + r][lane];
      acc13[r] += AccS[qs][28 + r][lane];
    }
    #pragma unroll
    for(int r = 0; r < 4; ++r){
      int row0 = qbase + g * 4 + r;
      int row1 = qbase + 16 + g * 4 + r;
      u16* x0 = XC + (size_t)(b * 2048 + row0) * 512 + h * 64 + li;
      u16* x1 = XC + (size_t)(b * 2048 + row1) * 512 + h * 64 + li;
      x0[0]  = f2bf(acc00[r]); x0[16] = f2bf(acc01[r]); x0[32] = f2bf(acc02[r]); x0[48] = f2bf(acc03[r]);
      x1[0]  = f2bf(acc10[r]); x1[16] = f2bf(acc11[r]); x1[32] = f2bf(acc12[r]); x1[48] = f2bf(acc13[r]);
    }
  }
}

// ---------------------------------------------------------------------------
// Out-projection + bias + residual + LayerNorm (unchanged — passed).
__global__ __launch_bounds__(512) void k_out(const u16* __restrict__ Xb,
                                             const u16* __restrict__ Wtp,
                                             float* __restrict__ Yf,
                                             const float* __restrict__ bias,
                                             const float* __restrict__ resid,
                                             const float* __restrict__ a2,
                                             const float* __restrict__ b2){
  __shared__ __align__(16) u16 Xs[16 * 520];
  __shared__ float sred[8][16], sqred[8][16], muL[16], rsL[16];
  const int t = threadIdx.x;
  const int lane = t & 63, w = t >> 6;
  const int g = lane >> 4, li = lane & 15;
  const int i0 = blockIdx.x * 16;
  const int n0 = w * 64;

  #pragma unroll
  for(int it = 0; it < 2; ++it){
    int s = it * 512 + t, row = s >> 6, c8 = s & 63;
    u16x8v xv = *(const u16x8v*)(Xb + (size_t)(i0 + row) * 512 + c8 * 8);
    *(u16x8v*)(Xs + row * 520 + c8 * 8) = xv;
  }
  __syncthreads();

  const u16* wp0 = Wtp + (size_t)(n0 +  0 + li) * 512 + g * 8;
  const u16* wp1 = Wtp + (size_t)(n0 + 16 + li) * 512 + g * 8;
  const u16* wp2 = Wtp + (size_t)(n0 + 32 + li) * 512 + g * 8;
  const u16* wp3 = Wtp + (size_t)(n0 + 48 + li) * 512 + g * 8;

#define LOADW(S, c) { \
  S##0 = *(const s16x8v*)(wp0 + (c) * 32); \
  S##1 = *(const s16x8v*)(wp1 + (c) * 32); \
  S##2 = *(const s16x8v*)(wp2 + (c) * 32); \
  S##3 = *(const s16x8v*)(wp3 + (c) * 32); }
#define COMPW(S, c) { \
  int k0 = (c) * 32 + g * 8; \
  s16x8v a0 = *(const s16x8v*)(Xs + li * 520 + k0); \
  acc[0] = mfma16(a0, S##0, acc[0]); \
  acc[1] = mfma16(a0, S##1, acc[1]); \
  acc[2] = mfma16(a0, S##2, acc[2]); \
  acc[3] = mfma16(a0, S##3, acc[3]); }

  f32x4v acc[4] = {};
  s16x8v wA0, wA1, wA2, wA3, wB0, wB1, wB2, wB3;
  LOADW(wA, 0);
  #pragma unroll
  for(int c = 0; c < 16; c += 2){
    LOADW(wB, c + 1);
    COMPW(wA, c);
    if(c + 2 < 16) LOADW(wA, c + 2);
    COMPW(wB, c + 1);
  }
#undef LOADW
#undef COMPW

  float zres[4][4];
  #pragma unroll
  for(int j = 0; j < 4; ++j){
    int n = n0 + j * 16 + li;
    float bv = bias[n];
    #pragma unroll
    for(int r = 0; r < 4; ++r){
      int i = i0 + g * 4 + r;
      zres[j][r] = acc[j][r] + bv + resid[(size_t)i * 512 + n];
    }
  }
  #pragma unroll
  for(int r = 0; r < 4; ++r){
    float S = 0.f, SQ = 0.f;
    #pragma unroll
    for(int j = 0; j < 4; ++j){ float zz = zres[j][r]; S += zz; SQ += zz * zz; }
    #pragma unroll
    for(int off = 1; off < 16; off <<= 1){ S += __shfl_xor(S, off, 16); SQ += __shfl_xor(SQ, off, 16); }
    if(li == 0){ sred[w][g * 4 + r] = S; sqred[w][g * 4 + r] = SQ; }
  }
  __syncthreads();
  if(t < 16){
    float S = 0.f, SQ = 0.f;
    #pragma unroll
    for(int ww = 0; ww < 8; ++ww){ S += sred[ww][t]; SQ += sqred[ww][t]; }
    float mu = S * (1.0f / 512.0f);
    float var = (SQ - 512.0f * mu * mu) * (1.0f / 511.0f);
    muL[t] = mu;
    rsL[t] = 1.0f / (sqrtf(fmaxf(var, 0.0f)) + 1e-3f);
  }
  __syncthreads();
  #pragma unroll
  for(int r = 0; r < 4; ++r){
    int rloc = g * 4 + r;
    float mu = muL[rloc], rs = rsL[rloc];
    size_t ib = (size_t)(i0 + rloc) * 512;
    #pragma unroll
    for(int j = 0; j < 4; ++j){
      int n = n0 + j * 16 + li;
      Yf[ib + n] = (zres[j][r] - mu) * rs * a2[n] + b2[n];
    }
  }
}

// ---------------------------------------------------------------------------
extern "C" void kernel_launch(void* const* d_in, const int* in_sizes, int n_in,
                              void* d_out, int out_size, void* d_ws, size_t ws_size,
                              hipStream_t stream){
  const float* q      = (const float*)d_in[0];
  const float* k      = (const float*)d_in[1];
  const float* v      = (const float*)d_in[2];
  const float* w_qs   = (const float*)d_in[3];
  const float* w_ks   = (const float*)d_in[4];
  const float* w_vs   = (const float*)d_in[5];
  const float* proj_w = (const float*)d_in[6];
  const float* proj_b = (const float*)d_in[7];
  const float* a2     = (const float*)d_in[8];
  const float* b2     = (const float*)d_in[9];

  char* ws = (char*)d_ws;
  u16* wt    = (u16*)(ws);                       // 3 x 512KB (q-weights pre-scaled)
  u16* wtp   = (u16*)(ws + 1572864);             // 512KB proj_w bf16
  u16* qhh   = (u16*)(ws + 2097152);             // 8 MB head-major
  u16* khh   = (u16*)(ws + 10485760);            // 8 MB head-major
  u16* vtt   = (u16*)(ws + 18874368);            // 8 MB [n][perm(i)]
  u16* xc    = (u16*)(ws + 27262976);            // 8 MB [i][512]

  float* out = (float*)d_out;                    // (4,2048,512) fp32
  float* att = out + 4194304;                    // (32,2048,2048) fp32

  // fold 1/sqrt(512) * log2(e) into the Q projection weights
  const float qscale = 0.06375872032774575f;

  k_wall<<<dim3(4096), 256, 0, stream>>>(w_qs, w_ks, w_vs, proj_w, wt, wtp, qscale);
  k_qkv <<<dim3(256, 6), 256, 0, stream>>>(q, k, v, wt, qhh, khh, vtt);
  k_attn<<<dim3(1024), 256, 0, stream>>>(qhh, khh, vtt, xc, att);
  k_out <<<dim3(512), 512, 0, stream>>>(xc, wtp, out, proj_b, q, a2, b2);
}